// Round 6
// baseline (343.482 us; speedup 1.0000x reference)
//
#include <hip/hip_runtime.h>

#define N_NODES 100000
#define N_EDGES 3200000
#define D_FEAT  128

#define RPB 128                              // rows per bucket (row >> 7)
#define NB ((N_NODES + RPB - 1) / RPB)       // 782 buckets
#define P3_EPT 16                            // edges per thread in partition
#define P3_TILE (256 * P3_EPT)               // 4096 edges per partition block
#define P3_GRID ((N_EDGES + P3_TILE - 1) / P3_TILE)   // 782
#define REFINE_CAP 7936                      // LDS staging cap (mean 4092, sigma 64)

// ---------------------------------------------------------------------------
// Pipeline:
//   1) bhist/bscan/partition: coarse counting-partition into 128-row buckets.
//   2) refine: per-bucket LDS counting sort to exact row order + rowptr.
//   3) csr_spmm: one wave per row, FOUR edges in flight per wave
//      (4 x 16-lane groups, 32B/lane), register accumulation, one coalesced
//      512B write per row. Latency-bound gather -> maximize MLP.
// ---------------------------------------------------------------------------

// P1: bucket histogram (per-block LDS hist, then flush).
__global__ __launch_bounds__(256) void bhist_kernel(
    const int* __restrict__ adj_rows, const int* __restrict__ idx_p,
    int* __restrict__ bhist)
{
    __shared__ int lh[NB];
    for (int i = threadIdx.x; i < NB; i += 256) lh[i] = 0;
    __syncthreads();
    const long long idx = (long long)idx_p[0];
    const int* rows = adj_rows + idx * (long long)N_EDGES;
    for (int e = blockIdx.x * blockDim.x + threadIdx.x; e < N_EDGES;
         e += gridDim.x * blockDim.x)
        atomicAdd(&lh[rows[e] >> 7], 1);
    __syncthreads();
    for (int i = threadIdx.x; i < NB; i += 256)
        if (lh[i]) atomicAdd(&bhist[i], lh[i]);
}

// P2: exclusive scan of NB bucket counts (single block), init cursors.
__global__ __launch_bounds__(1024) void bscan_kernel(
    const int* __restrict__ bhist, int* __restrict__ bptr,
    int* __restrict__ bcursor, int* __restrict__ rowptr)
{
    __shared__ int lds[1024];
    const int t = threadIdx.x;
    const int v = (t < NB) ? bhist[t] : 0;
    lds[t] = v;
    __syncthreads();
    for (int off = 1; off < 1024; off <<= 1) {
        int u = (t >= off) ? lds[t - off] : 0;
        __syncthreads();
        lds[t] += u;
        __syncthreads();
    }
    if (t < NB) {
        const int excl = lds[t] - v;
        bptr[t]    = excl;
        bcursor[t] = excl;
    }
    if (t == NB - 1) {
        bptr[NB] = lds[t];
        rowptr[N_NODES] = lds[t];
    }
}

// P3: partition edges into buckets. Per-block: LDS count -> reserve one
// contiguous run per bucket -> place. w0 = (row_lo << 24) | col, w1 = val.
__global__ __launch_bounds__(256) void partition_kernel(
    const int* __restrict__ adj_rows, const int* __restrict__ adj_cols,
    const float* __restrict__ adj_vals, const int* __restrict__ idx_p,
    int* __restrict__ bcursor, int2* __restrict__ pairs)
{
    __shared__ int lcnt[NB];
    __shared__ int lbase[NB];
    const long long idx = (long long)idx_p[0];
    const int*   rows = adj_rows + idx * (long long)N_EDGES;
    const int*   cols = adj_cols + idx * (long long)N_EDGES;
    const float* vals = adj_vals + idx * (long long)N_EDGES;

    const int tile = blockIdx.x * P3_TILE;
    for (int i = threadIdx.x; i < NB; i += 256) lcnt[i] = 0;
    __syncthreads();

    for (int k = 0; k < P3_EPT; ++k) {
        const int e = tile + k * 256 + (int)threadIdx.x;
        if (e < N_EDGES) atomicAdd(&lcnt[rows[e] >> 7], 1);
    }
    __syncthreads();

    for (int i = threadIdx.x; i < NB; i += 256) {
        const int c = lcnt[i];
        lbase[i] = c ? atomicAdd(&bcursor[i], c) : 0;
        lcnt[i]  = 0;
    }
    __syncthreads();

    for (int k = 0; k < P3_EPT; ++k) {
        const int e = tile + k * 256 + (int)threadIdx.x;
        if (e < N_EDGES) {
            const int r = rows[e];
            const int b = r >> 7;
            const int pos = lbase[b] + atomicAdd(&lcnt[b], 1);
            pairs[pos] = make_int2(((r & (RPB - 1)) << 24) | cols[e],
                                   __float_as_int(vals[e]));
        }
    }
}

// P4: per-bucket LDS counting sort to exact row order (in place) + rowptr.
__global__ __launch_bounds__(1024) void refine_kernel(
    int2* __restrict__ pairs, const int* __restrict__ bptr,
    int* __restrict__ rowptr)
{
    __shared__ int2 staged[REFINE_CAP];   // 63,488 B
    __shared__ int  hist[RPB];            // counts, then cursors
    __shared__ int  pfx[RPB];             // inclusive scan
    const int b    = blockIdx.x;
    const int t    = (int)threadIdx.x;
    const int base = bptr[b];
    const int n    = bptr[b + 1] - base;

    if (t < RPB) hist[t] = 0;
    __syncthreads();

    for (int i = t; i < n; i += 1024) {
        const int2 p = pairs[base + i];
        staged[i] = p;
        atomicAdd(&hist[((unsigned)p.x) >> 24], 1);
    }
    __syncthreads();

    if (t < RPB) pfx[t] = hist[t];
    __syncthreads();
    for (int off = 1; off < RPB; off <<= 1) {
        int u = (t < RPB && t >= off) ? pfx[t - off] : 0;
        __syncthreads();
        if (t < RPB) pfx[t] += u;
        __syncthreads();
    }
    if (t < RPB) {
        const int excl = pfx[t] - hist[t];
        const int row  = b * RPB + t;
        if (row < N_NODES) rowptr[row] = base + excl;
        hist[t] = excl;                    // becomes the cursor
    }
    __syncthreads();

    for (int i = t; i < n; i += 1024) {
        const int2 p   = staged[i];
        const int  pos = atomicAdd(&hist[((unsigned)p.x) >> 24], 1);
        pairs[base + pos] = p;            // write within 63KB L2 window
    }
}

// P5: CSR SpMM. One wave per row; 4 edges in flight (16-lane groups, 32B/lane).
__global__ __launch_bounds__(256) void csr_spmm_kernel(
    const float* __restrict__ x, const int* __restrict__ rowptr,
    const int2* __restrict__ pairs, float* __restrict__ out)
{
    const int wave = (int)(blockIdx.x * (blockDim.x >> 6) + (threadIdx.x >> 6));
    const int lane = (int)(threadIdx.x & 63);
    if (wave >= N_NODES) return;

    const int g  = lane >> 4;        // edge slot within a quad of edges
    const int sl = lane & 15;        // 8-float feature slot

    const int start = rowptr[wave];
    const int end   = rowptr[wave + 1];

    float4 a0 = make_float4(0.f, 0.f, 0.f, 0.f);
    float4 a1 = make_float4(0.f, 0.f, 0.f, 0.f);

    for (int chunk = start; chunk < end; chunk += 64) {
        const int m = min(64, end - chunk);
        int   w0 = 0;
        float v  = 0.f;                       // zero-fill: tail lanes no-op
        if (lane < m) {
            const int2 p = pairs[chunk + lane];   // coalesced 8B load
            w0 = p.x;
            v  = __int_as_float(p.y);
        }
        const int nq = (m + 3) >> 2;
#pragma unroll 4
        for (int j = 0; j < nq; ++j) {
            const int   src = 4 * j + g;
            const int   col = __shfl(w0, src) & 0xFFFFFF;
            const float vj  = __shfl(v, src);
            const float* xp = x + (size_t)col * D_FEAT + sl * 8;
            const float4 xv0 = *reinterpret_cast<const float4*>(xp);
            const float4 xv1 = *reinterpret_cast<const float4*>(xp + 4);
            a0.x += vj * xv0.x;  a0.y += vj * xv0.y;
            a0.z += vj * xv0.z;  a0.w += vj * xv0.w;
            a1.x += vj * xv1.x;  a1.y += vj * xv1.y;
            a1.z += vj * xv1.z;  a1.w += vj * xv1.w;
        }
    }

    // reduce the 4 group partials: lane ^ 16, then lane ^ 32.
    a0.x += __shfl_xor(a0.x, 16);  a0.y += __shfl_xor(a0.y, 16);
    a0.z += __shfl_xor(a0.z, 16);  a0.w += __shfl_xor(a0.w, 16);
    a1.x += __shfl_xor(a1.x, 16);  a1.y += __shfl_xor(a1.y, 16);
    a1.z += __shfl_xor(a1.z, 16);  a1.w += __shfl_xor(a1.w, 16);
    a0.x += __shfl_xor(a0.x, 32);  a0.y += __shfl_xor(a0.y, 32);
    a0.z += __shfl_xor(a0.z, 32);  a0.w += __shfl_xor(a0.w, 32);
    a1.x += __shfl_xor(a1.x, 32);  a1.y += __shfl_xor(a1.y, 32);
    a1.z += __shfl_xor(a1.z, 32);  a1.w += __shfl_xor(a1.w, 32);

    if (g == 0) {
        float* op = out + (size_t)wave * D_FEAT + sl * 8;
        *reinterpret_cast<float4*>(op)     = a0;
        *reinterpret_cast<float4*>(op + 4) = a1;
    }
}

// Fallback (tiny workspace): edge-parallel atomic kernel.
__global__ __launch_bounds__(256) void spmm_atomic_kernel(
    const float* __restrict__ x,
    const int*   __restrict__ adj_rows,
    const int*   __restrict__ adj_cols,
    const float* __restrict__ adj_vals,
    const int*   __restrict__ idx_p,
    float*       __restrict__ out)
{
    const long long idx = (long long)idx_p[0];
    const int*   rows = adj_rows + idx * (long long)N_EDGES;
    const int*   cols = adj_cols + idx * (long long)N_EDGES;
    const float* vals = adj_vals + idx * (long long)N_EDGES;

    long long tt = (long long)blockIdx.x * blockDim.x + threadIdx.x;
    long long e  = tt >> 5;
    int       f4 = (int)(tt & 31);
    if (e >= N_EDGES) return;

    const int   r = rows[e];
    const int   c = cols[e];
    const float v = vals[e];
    const float4 xv =
        *reinterpret_cast<const float4*>(x + (long long)c * D_FEAT + f4 * 4);
    float* o = out + (long long)r * D_FEAT + f4 * 4;
    unsafeAtomicAdd(o + 0, v * xv.x);
    unsafeAtomicAdd(o + 1, v * xv.y);
    unsafeAtomicAdd(o + 2, v * xv.z);
    unsafeAtomicAdd(o + 3, v * xv.w);
}

extern "C" void kernel_launch(void* const* d_in, const int* in_sizes, int n_in,
                              void* d_out, int out_size, void* d_ws, size_t ws_size,
                              hipStream_t stream) {
    const float* x        = (const float*)d_in[0];
    const int*   adj_rows = (const int*)  d_in[1];
    const int*   adj_cols = (const int*)  d_in[2];
    const float* adj_vals = (const float*)d_in[3];
    const int*   idx_p    = (const int*)  d_in[4];
    float*       out      = (float*)d_out;

    // Workspace layout (4-byte elements):
    //   bhist   : NB
    //   bptr    : NB+1
    //   bcursor : NB
    //   rowptr  : N_NODES+1
    //   pad     : to even offset (8B-align pairs)
    //   pairs   : N_EDGES int2
    const size_t n_meta_raw = (size_t)NB * 3 + 1 + (size_t)(N_NODES + 1);
    const size_t n_meta     = (n_meta_raw + 1) & ~(size_t)1;
    const size_t need       = (n_meta + (size_t)2 * N_EDGES) * 4;

    if (ws_size < need) {
        hipMemsetAsync(out, 0, (size_t)out_size * sizeof(float), stream);
        const long long total_threads = (long long)N_EDGES * 32;
        const int block = 256;
        const long long grid = (total_threads + block - 1) / block;
        spmm_atomic_kernel<<<(dim3)(unsigned)grid, block, 0, stream>>>(
            x, adj_rows, adj_cols, adj_vals, idx_p, out);
        return;
    }

    int*  bhist   = (int*)d_ws;
    int*  bptr    = bhist + NB;
    int*  bcursor = bptr + (NB + 1);
    int*  rowptr  = bcursor + NB;
    int2* pairs   = (int2*)((int*)d_ws + n_meta);

    hipMemsetAsync(bhist, 0, (size_t)NB * sizeof(int), stream);

    bhist_kernel<<<256, 256, 0, stream>>>(adj_rows, idx_p, bhist);
    bscan_kernel<<<1, 1024, 0, stream>>>(bhist, bptr, bcursor, rowptr);
    partition_kernel<<<P3_GRID, 256, 0, stream>>>(adj_rows, adj_cols, adj_vals,
                                                  idx_p, bcursor, pairs);
    refine_kernel<<<NB, 1024, 0, stream>>>(pairs, bptr, rowptr);

    const int rows_per_block = 256 / 64;  // 4 waves per block
    const int grid = (N_NODES + rows_per_block - 1) / rows_per_block;
    csr_spmm_kernel<<<grid, 256, 0, stream>>>(x, rowptr, pairs, out);
}

// Round 7
// 270.623 us; speedup vs baseline: 1.2692x; 1.2692x over previous
//
#include <hip/hip_runtime.h>

#define N_NODES 100000
#define N_EDGES 3200000
#define D_FEAT  128

#define RPB 128                              // rows per bucket (row >> 7)
#define NB ((N_NODES + RPB - 1) / RPB)       // 782 buckets
#define P3_EPT 32                            // edges per thread in partition
#define P3_TILE (256 * P3_EPT)               // 8192 edges per partition block
#define P3_GRID ((N_EDGES + P3_TILE - 1) / P3_TILE)   // 391
#define REFINE_CAP 7936                      // LDS staging cap (mean 4092, sigma 64)

// ---------------------------------------------------------------------------
// Pipeline:
//   0) cvt: x (f32) -> bf16 copy in d_ws. Halves gather bytes AND cache-line
//      requests in the SpMM (row = 256B). f32 accumulate keeps error ~0.1
//      vs threshold 0.3825.
//   1) bhist/bscan/partition: coarse counting-partition into 128-row buckets.
//   2) refine: per-bucket LDS counting sort to exact row order + rowptr.
//   3) csr_spmm_bf16: one wave per row, 4 edges per wave (16-lane groups,
//      one dwordx4 = 8 bf16 per lane), register f32 accumulation, one
//      coalesced 512B row write.
// R6 lesson: spmm is throughput-bound on the L2-miss fabric (~3.4 TB/s),
// not latency-bound -> reduce bytes, not MLP.
// ---------------------------------------------------------------------------

__device__ inline unsigned bf16rne(float f) {
    unsigned u = __float_as_uint(f);
    u += 0x7fffu + ((u >> 16) & 1u);
    return u >> 16;
}
__device__ inline unsigned pack2(float lo, float hi) {
    return bf16rne(lo) | (bf16rne(hi) << 16);
}

// P0: convert x to packed bf16 (uint4 = 8 features).
__global__ __launch_bounds__(256) void cvt_kernel(
    const float* __restrict__ x, uint4* __restrict__ xb)
{
    const int total = N_NODES * D_FEAT / 8;
    for (int i = blockIdx.x * 256 + threadIdx.x; i < total;
         i += gridDim.x * 256) {
        const float4 a = reinterpret_cast<const float4*>(x)[2 * i];
        const float4 b = reinterpret_cast<const float4*>(x)[2 * i + 1];
        uint4 o;
        o.x = pack2(a.x, a.y);
        o.y = pack2(a.z, a.w);
        o.z = pack2(b.x, b.y);
        o.w = pack2(b.z, b.w);
        xb[i] = o;
    }
}

// P1: bucket histogram (per-block LDS hist, then flush).
__global__ __launch_bounds__(256) void bhist_kernel(
    const int* __restrict__ adj_rows, const int* __restrict__ idx_p,
    int* __restrict__ bhist)
{
    __shared__ int lh[NB];
    for (int i = threadIdx.x; i < NB; i += 256) lh[i] = 0;
    __syncthreads();
    const long long idx = (long long)idx_p[0];
    const int* rows = adj_rows + idx * (long long)N_EDGES;
    for (int e = blockIdx.x * blockDim.x + threadIdx.x; e < N_EDGES;
         e += gridDim.x * blockDim.x)
        atomicAdd(&lh[rows[e] >> 7], 1);
    __syncthreads();
    for (int i = threadIdx.x; i < NB; i += 256)
        if (lh[i]) atomicAdd(&bhist[i], lh[i]);
}

// P2: exclusive scan of NB bucket counts (single block), init cursors.
__global__ __launch_bounds__(1024) void bscan_kernel(
    const int* __restrict__ bhist, int* __restrict__ bptr,
    int* __restrict__ bcursor, int* __restrict__ rowptr)
{
    __shared__ int lds[1024];
    const int t = threadIdx.x;
    const int v = (t < NB) ? bhist[t] : 0;
    lds[t] = v;
    __syncthreads();
    for (int off = 1; off < 1024; off <<= 1) {
        int u = (t >= off) ? lds[t - off] : 0;
        __syncthreads();
        lds[t] += u;
        __syncthreads();
    }
    if (t < NB) {
        const int excl = lds[t] - v;
        bptr[t]    = excl;
        bcursor[t] = excl;
    }
    if (t == NB - 1) {
        bptr[NB] = lds[t];
        rowptr[N_NODES] = lds[t];
    }
}

// P3: partition edges into buckets. Per-block: LDS count -> reserve one
// contiguous run per bucket -> place. w0 = (row_lo << 24) | col, w1 = val.
__global__ __launch_bounds__(256) void partition_kernel(
    const int* __restrict__ adj_rows, const int* __restrict__ adj_cols,
    const float* __restrict__ adj_vals, const int* __restrict__ idx_p,
    int* __restrict__ bcursor, int2* __restrict__ pairs)
{
    __shared__ int lcnt[NB];
    __shared__ int lbase[NB];
    const long long idx = (long long)idx_p[0];
    const int*   rows = adj_rows + idx * (long long)N_EDGES;
    const int*   cols = adj_cols + idx * (long long)N_EDGES;
    const float* vals = adj_vals + idx * (long long)N_EDGES;

    const int tile = blockIdx.x * P3_TILE;
    for (int i = threadIdx.x; i < NB; i += 256) lcnt[i] = 0;
    __syncthreads();

    for (int k = 0; k < P3_EPT; ++k) {
        const int e = tile + k * 256 + (int)threadIdx.x;
        if (e < N_EDGES) atomicAdd(&lcnt[rows[e] >> 7], 1);
    }
    __syncthreads();

    for (int i = threadIdx.x; i < NB; i += 256) {
        const int c = lcnt[i];
        lbase[i] = c ? atomicAdd(&bcursor[i], c) : 0;
        lcnt[i]  = 0;
    }
    __syncthreads();

    for (int k = 0; k < P3_EPT; ++k) {
        const int e = tile + k * 256 + (int)threadIdx.x;
        if (e < N_EDGES) {
            const int r = rows[e];
            const int b = r >> 7;
            const int pos = lbase[b] + atomicAdd(&lcnt[b], 1);
            pairs[pos] = make_int2(((r & (RPB - 1)) << 24) | cols[e],
                                   __float_as_int(vals[e]));
        }
    }
}

// P4: per-bucket LDS counting sort to exact row order (in place) + rowptr.
__global__ __launch_bounds__(1024) void refine_kernel(
    int2* __restrict__ pairs, const int* __restrict__ bptr,
    int* __restrict__ rowptr)
{
    __shared__ int2 staged[REFINE_CAP];   // 63,488 B
    __shared__ int  hist[RPB];            // counts, then cursors
    __shared__ int  pfx[RPB];             // inclusive scan
    const int b    = blockIdx.x;
    const int t    = (int)threadIdx.x;
    const int base = bptr[b];
    const int n    = bptr[b + 1] - base;

    if (t < RPB) hist[t] = 0;
    __syncthreads();

    for (int i = t; i < n; i += 1024) {
        const int2 p = pairs[base + i];
        staged[i] = p;
        atomicAdd(&hist[((unsigned)p.x) >> 24], 1);
    }
    __syncthreads();

    if (t < RPB) pfx[t] = hist[t];
    __syncthreads();
    for (int off = 1; off < RPB; off <<= 1) {
        int u = (t < RPB && t >= off) ? pfx[t - off] : 0;
        __syncthreads();
        if (t < RPB) pfx[t] += u;
        __syncthreads();
    }
    if (t < RPB) {
        const int excl = pfx[t] - hist[t];
        const int row  = b * RPB + t;
        if (row < N_NODES) rowptr[row] = base + excl;
        hist[t] = excl;                    // becomes the cursor
    }
    __syncthreads();

    for (int i = t; i < n; i += 1024) {
        const int2 p   = staged[i];
        const int  pos = atomicAdd(&hist[((unsigned)p.x) >> 24], 1);
        pairs[base + pos] = p;            // write within 63KB L2 window
    }
}

// P5: CSR SpMM on bf16 x. One wave per row; 4 edges per wave, 16-lane groups,
// one dwordx4 (8 bf16) per lane per edge. f32 accumulate.
__global__ __launch_bounds__(256) void csr_spmm_bf16_kernel(
    const uint4* __restrict__ xb, const int* __restrict__ rowptr,
    const int2* __restrict__ pairs, float* __restrict__ out)
{
    const int wave = (int)(blockIdx.x * (blockDim.x >> 6) + (threadIdx.x >> 6));
    const int lane = (int)(threadIdx.x & 63);
    if (wave >= N_NODES) return;

    const int g  = lane >> 4;        // edge slot within a quad of edges
    const int sl = lane & 15;        // 8-feature slot

    const int start = rowptr[wave];
    const int end   = rowptr[wave + 1];

    float4 a0 = make_float4(0.f, 0.f, 0.f, 0.f);
    float4 a1 = make_float4(0.f, 0.f, 0.f, 0.f);

    for (int chunk = start; chunk < end; chunk += 64) {
        const int m = min(64, end - chunk);
        int   w0 = 0;
        float v  = 0.f;                       // zero-fill: tail lanes no-op
        if (lane < m) {
            const int2 p = pairs[chunk + lane];   // coalesced 8B load
            w0 = p.x;
            v  = __int_as_float(p.y);
        }
        const int nq = (m + 3) >> 2;
#pragma unroll 4
        for (int j = 0; j < nq; ++j) {
            const int   src = 4 * j + g;
            const int   col = __shfl(w0, src) & 0xFFFFFF;
            const float vj  = __shfl(v, src);
            const uint4 w   = xb[(size_t)col * (D_FEAT / 8) + sl];
            a0.x += vj * __uint_as_float(w.x << 16);
            a0.y += vj * __uint_as_float(w.x & 0xffff0000u);
            a0.z += vj * __uint_as_float(w.y << 16);
            a0.w += vj * __uint_as_float(w.y & 0xffff0000u);
            a1.x += vj * __uint_as_float(w.z << 16);
            a1.y += vj * __uint_as_float(w.z & 0xffff0000u);
            a1.z += vj * __uint_as_float(w.w << 16);
            a1.w += vj * __uint_as_float(w.w & 0xffff0000u);
        }
    }

    // reduce the 4 group partials: lane ^ 16, then lane ^ 32.
    a0.x += __shfl_xor(a0.x, 16);  a0.y += __shfl_xor(a0.y, 16);
    a0.z += __shfl_xor(a0.z, 16);  a0.w += __shfl_xor(a0.w, 16);
    a1.x += __shfl_xor(a1.x, 16);  a1.y += __shfl_xor(a1.y, 16);
    a1.z += __shfl_xor(a1.z, 16);  a1.w += __shfl_xor(a1.w, 16);
    a0.x += __shfl_xor(a0.x, 32);  a0.y += __shfl_xor(a0.y, 32);
    a0.z += __shfl_xor(a0.z, 32);  a0.w += __shfl_xor(a0.w, 32);
    a1.x += __shfl_xor(a1.x, 32);  a1.y += __shfl_xor(a1.y, 32);
    a1.z += __shfl_xor(a1.z, 32);  a1.w += __shfl_xor(a1.w, 32);

    if (g == 0) {
        float* op = out + (size_t)wave * D_FEAT + sl * 8;
        *reinterpret_cast<float4*>(op)     = a0;
        *reinterpret_cast<float4*>(op + 4) = a1;
    }
}

// Mid fallback: f32 CSR SpMM (R5 structure, 2 edges per wave).
__global__ __launch_bounds__(256) void csr_spmm_f32_kernel(
    const float* __restrict__ x, const int* __restrict__ rowptr,
    const int2* __restrict__ pairs, float* __restrict__ out)
{
    const int wave = (int)(blockIdx.x * (blockDim.x >> 6) + (threadIdx.x >> 6));
    const int lane = (int)(threadIdx.x & 63);
    if (wave >= N_NODES) return;

    const int half = lane >> 5;
    const int sl   = lane & 31;

    const int start = rowptr[wave];
    const int end   = rowptr[wave + 1];

    float4 acc = make_float4(0.f, 0.f, 0.f, 0.f);
    for (int chunk = start; chunk < end; chunk += 64) {
        const int m = min(64, end - chunk);
        int   w0 = 0;
        float v  = 0.f;
        if (lane < m) {
            const int2 p = pairs[chunk + lane];
            w0 = p.x;
            v  = __int_as_float(p.y);
        }
        const int npair = (m + 1) >> 1;
#pragma unroll 4
        for (int j = 0; j < npair; ++j) {
            const int   src = 2 * j + half;
            const int   col = __shfl(w0, src) & 0xFFFFFF;
            const float vj  = __shfl(v, src);
            const float4 xv = *reinterpret_cast<const float4*>(
                x + (size_t)col * D_FEAT + sl * 4);
            acc.x += vj * xv.x;
            acc.y += vj * xv.y;
            acc.z += vj * xv.z;
            acc.w += vj * xv.w;
        }
    }
    acc.x += __shfl_xor(acc.x, 32);
    acc.y += __shfl_xor(acc.y, 32);
    acc.z += __shfl_xor(acc.z, 32);
    acc.w += __shfl_xor(acc.w, 32);
    if (half == 0)
        *reinterpret_cast<float4*>(out + (size_t)wave * D_FEAT + sl * 4) = acc;
}

// Last fallback (tiny workspace): edge-parallel atomic kernel.
__global__ __launch_bounds__(256) void spmm_atomic_kernel(
    const float* __restrict__ x,
    const int*   __restrict__ adj_rows,
    const int*   __restrict__ adj_cols,
    const float* __restrict__ adj_vals,
    const int*   __restrict__ idx_p,
    float*       __restrict__ out)
{
    const long long idx = (long long)idx_p[0];
    const int*   rows = adj_rows + idx * (long long)N_EDGES;
    const int*   cols = adj_cols + idx * (long long)N_EDGES;
    const float* vals = adj_vals + idx * (long long)N_EDGES;

    long long tt = (long long)blockIdx.x * blockDim.x + threadIdx.x;
    long long e  = tt >> 5;
    int       f4 = (int)(tt & 31);
    if (e >= N_EDGES) return;

    const int   r = rows[e];
    const int   c = cols[e];
    const float v = vals[e];
    const float4 xv =
        *reinterpret_cast<const float4*>(x + (long long)c * D_FEAT + f4 * 4);
    float* o = out + (long long)r * D_FEAT + f4 * 4;
    unsafeAtomicAdd(o + 0, v * xv.x);
    unsafeAtomicAdd(o + 1, v * xv.y);
    unsafeAtomicAdd(o + 2, v * xv.z);
    unsafeAtomicAdd(o + 3, v * xv.w);
}

extern "C" void kernel_launch(void* const* d_in, const int* in_sizes, int n_in,
                              void* d_out, int out_size, void* d_ws, size_t ws_size,
                              hipStream_t stream) {
    const float* x        = (const float*)d_in[0];
    const int*   adj_rows = (const int*)  d_in[1];
    const int*   adj_cols = (const int*)  d_in[2];
    const float* adj_vals = (const float*)d_in[3];
    const int*   idx_p    = (const int*)  d_in[4];
    float*       out      = (float*)d_out;

    // Workspace layout (4-byte elements):
    //   bhist   : NB
    //   bptr    : NB+1
    //   bcursor : NB
    //   rowptr  : N_NODES+1
    //   pad     : to multiple-of-4 ints (16B-align pairs & xb)
    //   pairs   : N_EDGES int2              (25.6 MB)
    //   xb      : N_NODES*D_FEAT bf16       (25.6 MB), only in full plan
    const size_t n_meta_raw = (size_t)NB * 3 + 1 + (size_t)(N_NODES + 1);
    const size_t n_meta     = (n_meta_raw + 3) & ~(size_t)3;
    const size_t need_f32   = (n_meta + (size_t)2 * N_EDGES) * 4;
    const size_t need_bf16  = need_f32 + (size_t)N_NODES * D_FEAT * 2;

    if (ws_size < need_f32) {
        hipMemsetAsync(out, 0, (size_t)out_size * sizeof(float), stream);
        const long long total_threads = (long long)N_EDGES * 32;
        const int block = 256;
        const long long grid = (total_threads + block - 1) / block;
        spmm_atomic_kernel<<<(dim3)(unsigned)grid, block, 0, stream>>>(
            x, adj_rows, adj_cols, adj_vals, idx_p, out);
        return;
    }

    int*  bhist   = (int*)d_ws;
    int*  bptr    = bhist + NB;
    int*  bcursor = bptr + (NB + 1);
    int*  rowptr  = bcursor + NB;
    int2* pairs   = (int2*)((int*)d_ws + n_meta);
    uint4* xb     = (uint4*)((int*)d_ws + n_meta + (size_t)2 * N_EDGES);

    hipMemsetAsync(bhist, 0, (size_t)NB * sizeof(int), stream);

    const bool use_bf16 = (ws_size >= need_bf16);
    if (use_bf16)
        cvt_kernel<<<2048, 256, 0, stream>>>(x, xb);

    bhist_kernel<<<256, 256, 0, stream>>>(adj_rows, idx_p, bhist);
    bscan_kernel<<<1, 1024, 0, stream>>>(bhist, bptr, bcursor, rowptr);
    partition_kernel<<<P3_GRID, 256, 0, stream>>>(adj_rows, adj_cols, adj_vals,
                                                  idx_p, bcursor, pairs);
    refine_kernel<<<NB, 1024, 0, stream>>>(pairs, bptr, rowptr);

    const int rows_per_block = 256 / 64;  // 4 waves per block
    const int grid = (N_NODES + rows_per_block - 1) / rows_per_block;
    if (use_bf16)
        csr_spmm_bf16_kernel<<<grid, 256, 0, stream>>>(xb, rowptr, pairs, out);
    else
        csr_spmm_f32_kernel<<<grid, 256, 0, stream>>>(x, rowptr, pairs, out);
}

// Round 8
// 250.744 us; speedup vs baseline: 1.3699x; 1.0793x over previous
//
#include <hip/hip_runtime.h>

#define N_NODES 100000
#define N_EDGES 3200000
#define D_FEAT  128

#define RPB 128                              // rows per bucket (row >> 7)
#define NB ((N_NODES + RPB - 1) / RPB)       // 782 buckets
#define P3_THREADS 512
#define P3_EPT 16                            // edges per thread in partition
#define P3_TILE (P3_THREADS * P3_EPT)        // 8192 edges per partition block
#define P3_GRID ((N_EDGES + P3_TILE - 1) / P3_TILE)   // 391
#define CAP 7936                             // LDS staging cap (mean 4092, sigma 64)

// ---------------------------------------------------------------------------
// Pipeline (R8):
//   0) cvt: x (f32) -> packed bf16 in d_ws (halves gather bytes; R7: -33% dur).
//   1) bhist/bscan: 128-row bucket histogram + exclusive scan.
//   2) partition: counting-partition edges into buckets (contiguous per-block
//      runs). 512 threads/block for TLP, same block count as R5.
//   3) sort_spmm (FUSED refine+spmm): one 1024-thr block per bucket.
//      Pass A: count rows (global pairs read, warms L2).
//      Pass B: scatter into LDS staged[] sorted by row (2nd read is L2-hot).
//      SpMM: one 16-lane group per row, 4 rows/wave, pair broadcast via LDS
//      same-address read, register f32 accumulation, one 512B row write.
//      No shfl, no tail waste, no global sorted-pairs round trip.
// R6/R7 lesson: spmm is fabric-throughput-bound (~3.8 TB/s TCC) -> cut bytes
// and overhead, not MLP.
// ---------------------------------------------------------------------------

__device__ inline unsigned bf16rne(float f) {
    unsigned u = __float_as_uint(f);
    u += 0x7fffu + ((u >> 16) & 1u);
    return u >> 16;
}
__device__ inline unsigned pack2(float lo, float hi) {
    return bf16rne(lo) | (bf16rne(hi) << 16);
}

// P0: convert x to packed bf16 (uint4 = 8 features).
__global__ __launch_bounds__(256) void cvt_kernel(
    const float* __restrict__ x, uint4* __restrict__ xb)
{
    const int total = N_NODES * D_FEAT / 8;
    for (int i = blockIdx.x * 256 + threadIdx.x; i < total;
         i += gridDim.x * 256) {
        const float4 a = reinterpret_cast<const float4*>(x)[2 * i];
        const float4 b = reinterpret_cast<const float4*>(x)[2 * i + 1];
        uint4 o;
        o.x = pack2(a.x, a.y);
        o.y = pack2(a.z, a.w);
        o.z = pack2(b.x, b.y);
        o.w = pack2(b.z, b.w);
        xb[i] = o;
    }
}

// P1: bucket histogram (per-block LDS hist, then flush).
__global__ __launch_bounds__(256) void bhist_kernel(
    const int* __restrict__ adj_rows, const int* __restrict__ idx_p,
    int* __restrict__ bhist)
{
    __shared__ int lh[NB];
    for (int i = threadIdx.x; i < NB; i += 256) lh[i] = 0;
    __syncthreads();
    const long long idx = (long long)idx_p[0];
    const int* rows = adj_rows + idx * (long long)N_EDGES;
    for (int e = blockIdx.x * blockDim.x + threadIdx.x; e < N_EDGES;
         e += gridDim.x * blockDim.x)
        atomicAdd(&lh[rows[e] >> 7], 1);
    __syncthreads();
    for (int i = threadIdx.x; i < NB; i += 256)
        if (lh[i]) atomicAdd(&bhist[i], lh[i]);
}

// P2: exclusive scan of NB bucket counts (single block), init cursors.
__global__ __launch_bounds__(1024) void bscan_kernel(
    const int* __restrict__ bhist, int* __restrict__ bptr,
    int* __restrict__ bcursor)
{
    __shared__ int lds[1024];
    const int t = threadIdx.x;
    const int v = (t < NB) ? bhist[t] : 0;
    lds[t] = v;
    __syncthreads();
    for (int off = 1; off < 1024; off <<= 1) {
        int u = (t >= off) ? lds[t - off] : 0;
        __syncthreads();
        lds[t] += u;
        __syncthreads();
    }
    if (t < NB) {
        const int excl = lds[t] - v;
        bptr[t]    = excl;
        bcursor[t] = excl;
    }
    if (t == NB - 1) bptr[NB] = lds[t];
}

// P3: partition edges into buckets. Per-block: LDS count -> reserve one
// contiguous run per bucket -> place. w0 = (row_lo << 24) | col, w1 = val.
__global__ __launch_bounds__(P3_THREADS) void partition_kernel(
    const int* __restrict__ adj_rows, const int* __restrict__ adj_cols,
    const float* __restrict__ adj_vals, const int* __restrict__ idx_p,
    int* __restrict__ bcursor, int2* __restrict__ pairs)
{
    __shared__ int lcnt[NB];
    __shared__ int lbase[NB];
    const long long idx = (long long)idx_p[0];
    const int*   rows = adj_rows + idx * (long long)N_EDGES;
    const int*   cols = adj_cols + idx * (long long)N_EDGES;
    const float* vals = adj_vals + idx * (long long)N_EDGES;

    const int tile = blockIdx.x * P3_TILE;
    for (int i = threadIdx.x; i < NB; i += P3_THREADS) lcnt[i] = 0;
    __syncthreads();

    for (int k = 0; k < P3_EPT; ++k) {
        const int e = tile + k * P3_THREADS + (int)threadIdx.x;
        if (e < N_EDGES) atomicAdd(&lcnt[rows[e] >> 7], 1);
    }
    __syncthreads();

    for (int i = threadIdx.x; i < NB; i += P3_THREADS) {
        const int c = lcnt[i];
        lbase[i] = c ? atomicAdd(&bcursor[i], c) : 0;
        lcnt[i]  = 0;
    }
    __syncthreads();

    for (int k = 0; k < P3_EPT; ++k) {
        const int e = tile + k * P3_THREADS + (int)threadIdx.x;
        if (e < N_EDGES) {
            const int r = rows[e];
            const int b = r >> 7;
            const int pos = lbase[b] + atomicAdd(&lcnt[b], 1);
            pairs[pos] = make_int2(((r & (RPB - 1)) << 24) | cols[e],
                                   __float_as_int(vals[e]));
        }
    }
}

// P4 (fused): per-bucket LDS counting sort + SpMM.
// One 1024-thr block per bucket; 16-lane group per row, 4 rows per wave.
__global__ __launch_bounds__(1024) void sort_spmm_kernel(
    const uint4* __restrict__ xb, const int* __restrict__ bptr,
    const int2* __restrict__ pairs, float* __restrict__ out)
{
    __shared__ int2 staged[CAP];          // 63,488 B, sorted by row_lo
    __shared__ int  rs[RPB + 1];          // row starts (exclusive scan)
    __shared__ int  cnt[RPB];             // counts, then cursors
    const int b    = blockIdx.x;
    const int t    = (int)threadIdx.x;
    const int base = bptr[b];
    const int n    = bptr[b + 1] - base;

    if (t < RPB) cnt[t] = 0;
    __syncthreads();

    // Pass A: count rows (also warms L2 with this bucket's pairs).
    for (int i = t; i < n; i += 1024)
        atomicAdd(&cnt[((unsigned)pairs[base + i].x) >> 24], 1);
    __syncthreads();

    // Exclusive scan of 128 counts (Hillis-Steele on first 128 threads).
    if (t < RPB) rs[t] = cnt[t];
    __syncthreads();
    for (int off = 1; off < RPB; off <<= 1) {
        int u = (t < RPB && t >= off) ? rs[t - off] : 0;
        __syncthreads();
        if (t < RPB) rs[t] += u;
        __syncthreads();
    }
    if (t < RPB) {
        const int incl = rs[t];
        const int excl = incl - cnt[t];
        rs[t]  = excl;
        cnt[t] = excl;                    // becomes the scatter cursor
        if (t == RPB - 1) rs[RPB] = incl;
    }
    __syncthreads();

    // Pass B: scatter into LDS sorted by row (re-read is L2-hot).
    for (int i = t; i < n; i += 1024) {
        const int2 p = pairs[base + i];
        const int pos = atomicAdd(&cnt[((unsigned)p.x) >> 24], 1);
        staged[pos] = p;
    }
    __syncthreads();

    // SpMM: group g of wave w handles rows (w*4+g) + 64*k, k=0,1.
    const int w    = t >> 6;
    const int lane = t & 63;
    const int g    = lane >> 4;          // group within wave
    const int sl   = lane & 15;          // 8-feature slot
    const int grp  = w * 4 + g;          // 0..63

    for (int k = 0; k < 2; ++k) {
        const int r   = grp + 64 * k;    // 0..127
        const int row = b * RPB + r;
        if (row >= N_NODES) break;
        const int s = rs[r];
        const int e = rs[r + 1];

        float4 a0 = make_float4(0.f, 0.f, 0.f, 0.f);
        float4 a1 = make_float4(0.f, 0.f, 0.f, 0.f);
        for (int j = s; j < e; ++j) {
            const int2  p   = staged[j];          // same-addr LDS broadcast
            const int   col = p.x & 0xFFFFFF;
            const float vj  = __int_as_float(p.y);
            const uint4 wv  = xb[(size_t)col * (D_FEAT / 8) + sl];
            a0.x += vj * __uint_as_float(wv.x << 16);
            a0.y += vj * __uint_as_float(wv.x & 0xffff0000u);
            a0.z += vj * __uint_as_float(wv.y << 16);
            a0.w += vj * __uint_as_float(wv.y & 0xffff0000u);
            a1.x += vj * __uint_as_float(wv.z << 16);
            a1.y += vj * __uint_as_float(wv.z & 0xffff0000u);
            a1.z += vj * __uint_as_float(wv.w << 16);
            a1.w += vj * __uint_as_float(wv.w & 0xffff0000u);
        }
        float* op = out + (size_t)row * D_FEAT + sl * 8;
        *reinterpret_cast<float4*>(op)     = a0;
        *reinterpret_cast<float4*>(op + 4) = a1;
    }
}

// Fallback (tiny workspace): edge-parallel atomic kernel.
__global__ __launch_bounds__(256) void spmm_atomic_kernel(
    const float* __restrict__ x,
    const int*   __restrict__ adj_rows,
    const int*   __restrict__ adj_cols,
    const float* __restrict__ adj_vals,
    const int*   __restrict__ idx_p,
    float*       __restrict__ out)
{
    const long long idx = (long long)idx_p[0];
    const int*   rows = adj_rows + idx * (long long)N_EDGES;
    const int*   cols = adj_cols + idx * (long long)N_EDGES;
    const float* vals = adj_vals + idx * (long long)N_EDGES;

    long long tt = (long long)blockIdx.x * blockDim.x + threadIdx.x;
    long long e  = tt >> 5;
    int       f4 = (int)(tt & 31);
    if (e >= N_EDGES) return;

    const int   r = rows[e];
    const int   c = cols[e];
    const float v = vals[e];
    const float4 xv =
        *reinterpret_cast<const float4*>(x + (long long)c * D_FEAT + f4 * 4);
    float* o = out + (long long)r * D_FEAT + f4 * 4;
    unsafeAtomicAdd(o + 0, v * xv.x);
    unsafeAtomicAdd(o + 1, v * xv.y);
    unsafeAtomicAdd(o + 2, v * xv.z);
    unsafeAtomicAdd(o + 3, v * xv.w);
}

extern "C" void kernel_launch(void* const* d_in, const int* in_sizes, int n_in,
                              void* d_out, int out_size, void* d_ws, size_t ws_size,
                              hipStream_t stream) {
    const float* x        = (const float*)d_in[0];
    const int*   adj_rows = (const int*)  d_in[1];
    const int*   adj_cols = (const int*)  d_in[2];
    const float* adj_vals = (const float*)d_in[3];
    const int*   idx_p    = (const int*)  d_in[4];
    float*       out      = (float*)d_out;

    // Workspace layout (4-byte elements):
    //   bhist   : NB
    //   bptr    : NB+1
    //   bcursor : NB
    //   pad     : to multiple-of-4 ints (16B-align pairs & xb)
    //   pairs   : N_EDGES int2              (25.6 MB)
    //   xb      : N_NODES*D_FEAT bf16       (25.6 MB)
    const size_t n_meta_raw = (size_t)NB * 3 + 1;
    const size_t n_meta     = (n_meta_raw + 3) & ~(size_t)3;
    const size_t need       = (n_meta + (size_t)2 * N_EDGES) * 4
                            + (size_t)N_NODES * D_FEAT * 2;

    if (ws_size < need) {
        hipMemsetAsync(out, 0, (size_t)out_size * sizeof(float), stream);
        const long long total_threads = (long long)N_EDGES * 32;
        const int block = 256;
        const long long grid = (total_threads + block - 1) / block;
        spmm_atomic_kernel<<<(dim3)(unsigned)grid, block, 0, stream>>>(
            x, adj_rows, adj_cols, adj_vals, idx_p, out);
        return;
    }

    int*   bhist   = (int*)d_ws;
    int*   bptr    = bhist + NB;
    int*   bcursor = bptr + (NB + 1);
    int2*  pairs   = (int2*)((int*)d_ws + n_meta);
    uint4* xb      = (uint4*)((int*)d_ws + n_meta + (size_t)2 * N_EDGES);

    hipMemsetAsync(bhist, 0, (size_t)NB * sizeof(int), stream);

    cvt_kernel<<<2048, 256, 0, stream>>>(x, xb);
    bhist_kernel<<<256, 256, 0, stream>>>(adj_rows, idx_p, bhist);
    bscan_kernel<<<1, 1024, 0, stream>>>(bhist, bptr, bcursor);
    partition_kernel<<<P3_GRID, P3_THREADS, 0, stream>>>(
        adj_rows, adj_cols, adj_vals, idx_p, bcursor, pairs);
    sort_spmm_kernel<<<NB, 1024, 0, stream>>>(xb, bptr, pairs, out);
}

// Round 9
// 232.655 us; speedup vs baseline: 1.4764x; 1.0777x over previous
//
#include <hip/hip_runtime.h>

#define N_NODES 100000
#define N_EDGES 3200000
#define D_FEAT  128

#define RPB 128                              // rows per bucket (row >> 7)
#define NB ((N_NODES + RPB - 1) / RPB)       // 782 buckets
#define P3_THREADS 512
#define P3_EPT 16                            // edges per thread in partition
#define P3_TILE (P3_THREADS * P3_EPT)        // 8192 edges per partition block
#define P3_GRID ((N_EDGES + P3_TILE - 1) / P3_TILE)   // 391

#define NS 25                                // col slices (col >> 12, 1MB bf16 each)
#define NCELL (RPB * NS)                     // 3200 sort cells
#define CAP 4608                             // LDS staging cap (bucket max ~4326 @8sigma)

#define CVT_BLOCKS 2048
#define HIST_BLOCKS 256

// ---------------------------------------------------------------------------
// Pipeline (R9):
//   0) cvt_bhist (FUSED): blocks [0,2048) convert x -> packed bf16;
//      blocks [2048,2304) build the 128-row bucket histogram.
//   1) bscan: exclusive scan of NB bucket counts.
//   2) partition: counting-partition edges into 128-row buckets.
//   3) sort_spmm: one 1024-thr block per bucket. In-LDS counting sort with
//      2-level key (row_lo, col>>12): each row's edges end up in ascending
//      col-slice order, so all groups sweep x left-to-right together ->
//      the instantaneous gather window (~2 slices ~ 2MB) fits per-XCD L2.
//      SpMM: 16-lane group per row, LDS same-addr broadcast of (col,val),
//      f32 register accumulation, one 512B coalesced row write.
// R6-R8 lesson: spmm is fabric-throughput-bound (~3.8 TB/s TCC miss path);
// the only remaining byte lever is L2 hit rate -> engineered col locality.
// ---------------------------------------------------------------------------

__device__ inline unsigned bf16rne(float f) {
    unsigned u = __float_as_uint(f);
    u += 0x7fffu + ((u >> 16) & 1u);
    return u >> 16;
}
__device__ inline unsigned pack2(float lo, float hi) {
    return bf16rne(lo) | (bf16rne(hi) << 16);
}

// P0: fused x->bf16 convert (blocks < CVT_BLOCKS) + bucket histogram (rest).
__global__ __launch_bounds__(256) void cvt_bhist_kernel(
    const float* __restrict__ x, uint4* __restrict__ xb,
    const int* __restrict__ adj_rows, const int* __restrict__ idx_p,
    int* __restrict__ bhist)
{
    __shared__ int lh[NB];
    if (blockIdx.x < CVT_BLOCKS) {
        const int total = N_NODES * D_FEAT / 8;
        for (int i = blockIdx.x * 256 + threadIdx.x; i < total;
             i += CVT_BLOCKS * 256) {
            const float4 a = reinterpret_cast<const float4*>(x)[2 * i];
            const float4 b = reinterpret_cast<const float4*>(x)[2 * i + 1];
            uint4 o;
            o.x = pack2(a.x, a.y);
            o.y = pack2(a.z, a.w);
            o.z = pack2(b.x, b.y);
            o.w = pack2(b.z, b.w);
            xb[i] = o;
        }
    } else {
        for (int i = threadIdx.x; i < NB; i += 256) lh[i] = 0;
        __syncthreads();
        const long long idx = (long long)idx_p[0];
        const int* rows = adj_rows + idx * (long long)N_EDGES;
        for (int e = (blockIdx.x - CVT_BLOCKS) * 256 + threadIdx.x;
             e < N_EDGES; e += HIST_BLOCKS * 256)
            atomicAdd(&lh[rows[e] >> 7], 1);
        __syncthreads();
        for (int i = threadIdx.x; i < NB; i += 256)
            if (lh[i]) atomicAdd(&bhist[i], lh[i]);
    }
}

// P1: exclusive scan of NB bucket counts (single block), init cursors.
__global__ __launch_bounds__(1024) void bscan_kernel(
    const int* __restrict__ bhist, int* __restrict__ bptr,
    int* __restrict__ bcursor)
{
    __shared__ int lds[1024];
    const int t = threadIdx.x;
    const int v = (t < NB) ? bhist[t] : 0;
    lds[t] = v;
    __syncthreads();
    for (int off = 1; off < 1024; off <<= 1) {
        int u = (t >= off) ? lds[t - off] : 0;
        __syncthreads();
        lds[t] += u;
        __syncthreads();
    }
    if (t < NB) {
        const int excl = lds[t] - v;
        bptr[t]    = excl;
        bcursor[t] = excl;
    }
    if (t == NB - 1) bptr[NB] = lds[t];
}

// P2: partition edges into buckets. Per-block: LDS count -> reserve one
// contiguous run per bucket -> place. w0 = (row_lo << 24) | col, w1 = val.
__global__ __launch_bounds__(P3_THREADS) void partition_kernel(
    const int* __restrict__ adj_rows, const int* __restrict__ adj_cols,
    const float* __restrict__ adj_vals, const int* __restrict__ idx_p,
    int* __restrict__ bcursor, int2* __restrict__ pairs)
{
    __shared__ int lcnt[NB];
    __shared__ int lbase[NB];
    const long long idx = (long long)idx_p[0];
    const int*   rows = adj_rows + idx * (long long)N_EDGES;
    const int*   cols = adj_cols + idx * (long long)N_EDGES;
    const float* vals = adj_vals + idx * (long long)N_EDGES;

    const int tile = blockIdx.x * P3_TILE;
    for (int i = threadIdx.x; i < NB; i += P3_THREADS) lcnt[i] = 0;
    __syncthreads();

    for (int k = 0; k < P3_EPT; ++k) {
        const int e = tile + k * P3_THREADS + (int)threadIdx.x;
        if (e < N_EDGES) atomicAdd(&lcnt[rows[e] >> 7], 1);
    }
    __syncthreads();

    for (int i = threadIdx.x; i < NB; i += P3_THREADS) {
        const int c = lcnt[i];
        lbase[i] = c ? atomicAdd(&bcursor[i], c) : 0;
        lcnt[i]  = 0;
    }
    __syncthreads();

    for (int k = 0; k < P3_EPT; ++k) {
        const int e = tile + k * P3_THREADS + (int)threadIdx.x;
        if (e < N_EDGES) {
            const int r = rows[e];
            const int b = r >> 7;
            const int pos = lbase[b] + atomicAdd(&lcnt[b], 1);
            pairs[pos] = make_int2(((r & (RPB - 1)) << 24) | cols[e],
                                   __float_as_int(vals[e]));
        }
    }
}

// P3 (fused sort+spmm): per-bucket 2-level LDS counting sort + SpMM.
__global__ __launch_bounds__(1024) void sort_spmm_kernel(
    const uint4* __restrict__ xb, const int* __restrict__ bptr,
    const int2* __restrict__ pairs, float* __restrict__ out)
{
    __shared__ int2 staged[CAP];          // 36,864 B, sorted by (row, colslice)
    __shared__ int  cellptr[NCELL];       // 12,800 B: counts -> scan -> cursors
    __shared__ int  rs[RPB + 1];          //    516 B: per-row start
    __shared__ int  scan[1024];           //  4,096 B
    const int b    = blockIdx.x;
    const int t    = (int)threadIdx.x;
    const int base = bptr[b];
    const int n    = bptr[b + 1] - base;

    for (int i = t; i < NCELL; i += 1024) cellptr[i] = 0;
    __syncthreads();

    // Pass A: count cells (key = row_lo * NS + col_slice).
    for (int i = t; i < n; i += 1024) {
        const int2 p = pairs[base + i];
        const int row = ((unsigned)p.x) >> 24;
        const int col = p.x & 0xFFFFFF;
        atomicAdd(&cellptr[row * NS + (col >> 12)], 1);
    }
    __syncthreads();

    // Exclusive scan over NCELL cells: thread t owns cells [4t, 4t+4).
    const int i0 = t * 4;
    int v0 = 0, v1 = 0, v2 = 0, v3 = 0;
    if (i0 + 0 < NCELL) v0 = cellptr[i0 + 0];
    if (i0 + 1 < NCELL) v1 = cellptr[i0 + 1];
    if (i0 + 2 < NCELL) v2 = cellptr[i0 + 2];
    if (i0 + 3 < NCELL) v3 = cellptr[i0 + 3];
    const int s = v0 + v1 + v2 + v3;
    scan[t] = s;
    __syncthreads();
    for (int off = 1; off < 1024; off <<= 1) {
        int u = (t >= off) ? scan[t - off] : 0;
        __syncthreads();
        scan[t] += u;
        __syncthreads();
    }
    int run = scan[t] - s;                // exclusive prefix for cell i0
    if (i0 + 0 < NCELL) { cellptr[i0 + 0] = run; run += v0; }
    if (i0 + 1 < NCELL) { cellptr[i0 + 1] = run; run += v1; }
    if (i0 + 2 < NCELL) { cellptr[i0 + 2] = run; run += v2; }
    if (i0 + 3 < NCELL) { cellptr[i0 + 3] = run; run += v3; }
    __syncthreads();

    // Row starts (before cellptr mutates into cursors).
    if (t < RPB) rs[t] = cellptr[t * NS];
    if (t == 0)  rs[RPB] = n;
    __syncthreads();

    // Pass B: scatter into LDS sorted by (row, colslice).
    for (int i = t; i < n; i += 1024) {
        const int2 p = pairs[base + i];
        const int row = ((unsigned)p.x) >> 24;
        const int col = p.x & 0xFFFFFF;
        const int pos = atomicAdd(&cellptr[row * NS + (col >> 12)], 1);
        if (pos < CAP) staged[pos] = p;
    }
    __syncthreads();

    // SpMM: group g of wave w handles rows (w*4+g) + 64*k, k=0,1.
    const int w    = t >> 6;
    const int lane = t & 63;
    const int g    = lane >> 4;          // group within wave
    const int sl   = lane & 15;          // 8-feature slot
    const int grp  = w * 4 + g;          // 0..63

    for (int k = 0; k < 2; ++k) {
        const int r   = grp + 64 * k;    // 0..127
        const int row = b * RPB + r;
        if (row >= N_NODES) break;
        const int s0 = rs[r];
        const int e0 = rs[r + 1];

        float4 a0 = make_float4(0.f, 0.f, 0.f, 0.f);
        float4 a1 = make_float4(0.f, 0.f, 0.f, 0.f);
        for (int j = s0; j < e0; ++j) {
            const int2  p   = staged[j];          // same-addr LDS broadcast
            const int   col = p.x & 0xFFFFFF;
            const float vj  = __int_as_float(p.y);
            const uint4 wv  = xb[(size_t)col * (D_FEAT / 8) + sl];
            a0.x += vj * __uint_as_float(wv.x << 16);
            a0.y += vj * __uint_as_float(wv.x & 0xffff0000u);
            a0.z += vj * __uint_as_float(wv.y << 16);
            a0.w += vj * __uint_as_float(wv.y & 0xffff0000u);
            a1.x += vj * __uint_as_float(wv.z << 16);
            a1.y += vj * __uint_as_float(wv.z & 0xffff0000u);
            a1.z += vj * __uint_as_float(wv.w << 16);
            a1.w += vj * __uint_as_float(wv.w & 0xffff0000u);
        }
        float* op = out + (size_t)row * D_FEAT + sl * 8;
        *reinterpret_cast<float4*>(op)     = a0;
        *reinterpret_cast<float4*>(op + 4) = a1;
    }
}

// Fallback (tiny workspace): edge-parallel atomic kernel.
__global__ __launch_bounds__(256) void spmm_atomic_kernel(
    const float* __restrict__ x,
    const int*   __restrict__ adj_rows,
    const int*   __restrict__ adj_cols,
    const float* __restrict__ adj_vals,
    const int*   __restrict__ idx_p,
    float*       __restrict__ out)
{
    const long long idx = (long long)idx_p[0];
    const int*   rows = adj_rows + idx * (long long)N_EDGES;
    const int*   cols = adj_cols + idx * (long long)N_EDGES;
    const float* vals = adj_vals + idx * (long long)N_EDGES;

    long long tt = (long long)blockIdx.x * blockDim.x + threadIdx.x;
    long long e  = tt >> 5;
    int       f4 = (int)(tt & 31);
    if (e >= N_EDGES) return;

    const int   r = rows[e];
    const int   c = cols[e];
    const float v = vals[e];
    const float4 xv =
        *reinterpret_cast<const float4*>(x + (long long)c * D_FEAT + f4 * 4);
    float* o = out + (long long)r * D_FEAT + f4 * 4;
    unsafeAtomicAdd(o + 0, v * xv.x);
    unsafeAtomicAdd(o + 1, v * xv.y);
    unsafeAtomicAdd(o + 2, v * xv.z);
    unsafeAtomicAdd(o + 3, v * xv.w);
}

extern "C" void kernel_launch(void* const* d_in, const int* in_sizes, int n_in,
                              void* d_out, int out_size, void* d_ws, size_t ws_size,
                              hipStream_t stream) {
    const float* x        = (const float*)d_in[0];
    const int*   adj_rows = (const int*)  d_in[1];
    const int*   adj_cols = (const int*)  d_in[2];
    const float* adj_vals = (const float*)d_in[3];
    const int*   idx_p    = (const int*)  d_in[4];
    float*       out      = (float*)d_out;

    // Workspace layout (4-byte elements):
    //   bhist   : NB
    //   bptr    : NB+1
    //   bcursor : NB
    //   pad     : to multiple-of-4 ints (16B-align pairs & xb)
    //   pairs   : N_EDGES int2              (25.6 MB)
    //   xb      : N_NODES*D_FEAT bf16       (25.6 MB)
    const size_t n_meta_raw = (size_t)NB * 3 + 1;
    const size_t n_meta     = (n_meta_raw + 3) & ~(size_t)3;
    const size_t need       = (n_meta + (size_t)2 * N_EDGES) * 4
                            + (size_t)N_NODES * D_FEAT * 2;

    if (ws_size < need) {
        hipMemsetAsync(out, 0, (size_t)out_size * sizeof(float), stream);
        const long long total_threads = (long long)N_EDGES * 32;
        const int block = 256;
        const long long grid = (total_threads + block - 1) / block;
        spmm_atomic_kernel<<<(dim3)(unsigned)grid, block, 0, stream>>>(
            x, adj_rows, adj_cols, adj_vals, idx_p, out);
        return;
    }

    int*   bhist   = (int*)d_ws;
    int*   bptr    = bhist + NB;
    int*   bcursor = bptr + (NB + 1);
    int2*  pairs   = (int2*)((int*)d_ws + n_meta);
    uint4* xb      = (uint4*)((int*)d_ws + n_meta + (size_t)2 * N_EDGES);

    hipMemsetAsync(bhist, 0, (size_t)NB * sizeof(int), stream);

    cvt_bhist_kernel<<<CVT_BLOCKS + HIST_BLOCKS, 256, 0, stream>>>(
        x, xb, adj_rows, idx_p, bhist);
    bscan_kernel<<<1, 1024, 0, stream>>>(bhist, bptr, bcursor);
    partition_kernel<<<P3_GRID, P3_THREADS, 0, stream>>>(
        adj_rows, adj_cols, adj_vals, idx_p, bcursor, pairs);
    sort_spmm_kernel<<<NB, 1024, 0, stream>>>(xb, bptr, pairs, out);
}